// Round 1
// baseline (371.419 us; speedup 1.0000x reference)
//
#include <hip/hip_runtime.h>

#define N_NODES 20000
#define N_EDGES 160000
#define CIN     2000
#define KP1     2048   // CIN padded to mult of 32
#define N1      500
#define N1P     512
#define N2      250
#define N2P     256

typedef __attribute__((ext_vector_type(4))) float f32x4;
typedef __attribute__((ext_vector_type(8))) __bf16 bf16x8;
typedef __attribute__((ext_vector_type(8))) unsigned short ushort8;

typedef const __attribute__((address_space(1))) void* as1cv;
typedef __attribute__((address_space(3))) void* as3v;

__device__ __forceinline__ unsigned short f2bf(float f) {
    unsigned int u = __builtin_bit_cast(unsigned int, f);
    u += 0x7FFFu + ((u >> 16) & 1u);   // RNE
    return (unsigned short)(u >> 16);
}

// ---------------- graph prep ----------------
__global__ void k_init(float* deg, int* cnt, int* cursor) {
    int i = blockIdx.x * 256 + threadIdx.x;
    if (i < N_NODES) { deg[i] = 1.0f; cnt[i] = 0; cursor[i] = 0; }
}

__global__ void k_count(const int* __restrict__ ei, const float* __restrict__ ew,
                        float* deg, int* cnt) {
    int e = blockIdx.x * 256 + threadIdx.x;
    if (e < N_EDGES) {
        int d = ei[N_EDGES + e];
        atomicAdd(&deg[d], ew[e]);
        atomicAdd(&cnt[d], 1);
    }
}

__global__ void k_dinv(const float* __restrict__ deg, float* __restrict__ dinv) {
    int i = blockIdx.x * 256 + threadIdx.x;
    if (i < N_NODES) dinv[i] = rsqrtf(deg[i]);   // deg >= 1 always (self loop)
}

__global__ void scan_kernel(const int* __restrict__ cnt, int* __restrict__ rowPtr) {
    __shared__ int buf[1024];
    __shared__ int carry;
    int t = threadIdx.x;
    if (t == 0) { carry = 0; rowPtr[0] = 0; }
    __syncthreads();
    for (int base = 0; base < N_NODES; base += 1024) {
        int i = base + t;
        int v = (i < N_NODES) ? cnt[i] : 0;
        buf[t] = v;
        __syncthreads();
        for (int off = 1; off < 1024; off <<= 1) {
            int x = (t >= off) ? buf[t - off] : 0;
            __syncthreads();
            buf[t] += x;
            __syncthreads();
        }
        int inc = buf[t] + carry;
        if (i < N_NODES) rowPtr[i + 1] = inc;
        __syncthreads();
        if (t == 1023) carry = inc;
        __syncthreads();
    }
}

__global__ void k_fill(const int* __restrict__ ei, const float* __restrict__ ew,
                       const float* __restrict__ dinv, const int* __restrict__ rowPtr,
                       int* cursor, int* __restrict__ colA, float* __restrict__ valA) {
    int e = blockIdx.x * 256 + threadIdx.x;
    if (e < N_EDGES) {
        int s = ei[e], d = ei[N_EDGES + e];
        int p = atomicAdd(&cursor[d], 1);
        int j = rowPtr[d] + p;
        colA[j] = s;
        valA[j] = dinv[s] * ew[e] * dinv[d];
    }
}

// ---------------- f32 -> bf16 conversion (padded) ----------------
__global__ void conv_x(const float* __restrict__ X, unsigned int* __restrict__ Xb) {
    int idx = blockIdx.x * 256 + threadIdx.x;          // pair index, row stride 1024 pairs
    if (idx >= N_NODES * (KP1 / 2)) return;
    int m = idx >> 10, c = idx & 1023;
    int k = c * 2;
    unsigned int o = 0;
    if (k < CIN) {
        float2 v = *reinterpret_cast<const float2*>(X + (size_t)m * CIN + k);
        o = (unsigned int)f2bf(v.x) | ((unsigned int)f2bf(v.y) << 16);
    }
    Xb[idx] = o;
}

__global__ void conv_w(const float* __restrict__ W, unsigned int* __restrict__ Wb,
                       int total, int rows, int cols, int pairsPerRow) {
    int idx = blockIdx.x * 256 + threadIdx.x;
    if (idx >= total) return;
    int r = idx / pairsPerRow;
    int c = idx - r * pairsPerRow;
    int k = c * 2;
    unsigned int o = 0;
    if (r < rows && k < cols) {
        float2 v = *reinterpret_cast<const float2*>(W + (size_t)r * cols + k);
        o = (unsigned int)f2bf(v.x) | ((unsigned int)f2bf(v.y) << 16);
    }
    Wb[idx] = o;
}

// ---------------- bf16 MFMA GEMM: C[M,N] = A[M,K] * B[N,K]^T ----------------
// A,B bf16 row-major K-contiguous (K = lda = ldb, multiple of 32).
// 128x128 tile, BK=32, 4 waves, 16x16x32 MFMA, global_load_lds staging.
__global__ __launch_bounds__(256) void gemm_bt(
    const unsigned short* __restrict__ A, const unsigned short* __restrict__ B,
    float* __restrict__ C, int M, int lda, int ldb, int ldc, int nk) {
    __shared__ alignas(16) unsigned short lA[128 * 32];
    __shared__ alignas(16) unsigned short lB[128 * 32];
    const int t = threadIdx.x;
    const int w = t >> 6, lane = t & 63;
    const int bm0 = blockIdx.y * 128, bn0 = blockIdx.x * 128;
    const int wr = w >> 1, wc = w & 1;               // wave -> 64x64 quadrant
    const int lr = lane & 15, lk = (lane >> 4) * 8;  // fragment row / k-offset

    f32x4 acc[4][4];
#pragma unroll
    for (int i = 0; i < 4; i++)
#pragma unroll
        for (int j = 0; j < 4; j++) acc[i][j] = (f32x4){0.f, 0.f, 0.f, 0.f};

    for (int kt = 0; kt < nk; ++kt) {
        const int kb = kt * 32;
        // stage A tile [128][32]: 512 16B-chunks; chunk = row*4 + kgroup
#pragma unroll
        for (int i = 0; i < 2; i++) {
            int c0 = i * 256 + w * 64;
            int c  = c0 + lane;
            int r = c >> 2, kg = c & 3;
            int grow = bm0 + r; grow = grow < M ? grow : M - 1;
            const unsigned short* gp = A + (size_t)grow * lda + kb + kg * 8;
            __builtin_amdgcn_global_load_lds((as1cv)gp, (as3v)(lA + (size_t)c0 * 8), 16, 0, 0);
        }
#pragma unroll
        for (int i = 0; i < 2; i++) {
            int c0 = i * 256 + w * 64;
            int c  = c0 + lane;
            int r = c >> 2, kg = c & 3;
            const unsigned short* gp = B + (size_t)(bn0 + r) * ldb + kb + kg * 8;
            __builtin_amdgcn_global_load_lds((as1cv)gp, (as3v)(lB + (size_t)c0 * 8), 16, 0, 0);
        }
        __syncthreads();
        ushort8 af[4], bfr[4];
#pragma unroll
        for (int m = 0; m < 4; m++)
            af[m] = *reinterpret_cast<const ushort8*>(&lA[(wr * 64 + m * 16 + lr) * 32 + lk]);
#pragma unroll
        for (int n = 0; n < 4; n++)
            bfr[n] = *reinterpret_cast<const ushort8*>(&lB[(wc * 64 + n * 16 + lr) * 32 + lk]);
#pragma unroll
        for (int m = 0; m < 4; m++)
#pragma unroll
            for (int n = 0; n < 4; n++)
                acc[m][n] = __builtin_amdgcn_mfma_f32_16x16x32_bf16(
                    __builtin_bit_cast(bf16x8, af[m]), __builtin_bit_cast(bf16x8, bfr[n]),
                    acc[m][n], 0, 0, 0);
        __syncthreads();
    }
    // epilogue: C/D layout col = lane&15, row = (lane>>4)*4 + reg   [m89-verified]
    const int crow0 = bm0 + wr * 64 + (lane >> 4) * 4;
    const int ccol0 = bn0 + wc * 64 + lr;
#pragma unroll
    for (int m = 0; m < 4; m++)
#pragma unroll
        for (int n = 0; n < 4; n++)
#pragma unroll
            for (int r = 0; r < 4; r++) {
                int row = crow0 + m * 16 + r;
                if (row < M) C[(size_t)row * ldc + ccol0 + n * 16] = acc[m][n][r];
            }
}

// ---------------- aggregation 1: AG1 = A_hat @ H1 + b1, bf16 out [20000][512] ----------------
__global__ __launch_bounds__(256) void agg1(
    const float* __restrict__ H1, const int* __restrict__ rowPtr,
    const int* __restrict__ colA, const float* __restrict__ valA,
    const float* __restrict__ dinv, const float* __restrict__ b1,
    unsigned short* __restrict__ AG1) {
    int d = blockIdx.x, t = threadIdx.x;
    float self = dinv[d]; self *= self;
    const float* hd = H1 + (size_t)d * N1P;
    int f1 = t + 256;
    float a0 = self * hd[t];
    float a1 = (f1 < N1) ? self * hd[f1] : 0.f;
    int e0 = rowPtr[d], e1 = rowPtr[d + 1];
    for (int e = e0; e < e1; ++e) {
        int s = colA[e];
        float wv = valA[e];
        const float* hs = H1 + (size_t)s * N1P;
        a0 += wv * hs[t];
        if (f1 < N1) a1 += wv * hs[f1];
    }
    AG1[(size_t)d * N1P + t] = f2bf(a0 + b1[t]);
    AG1[(size_t)d * N1P + f1] = (f1 < N1) ? f2bf(a1 + b1[f1]) : (unsigned short)0;
}

// ---------------- aggregation 2: AG2 = A_hat @ H2 + b2, f32 out [20000][256] ----------------
__global__ __launch_bounds__(128) void agg2(
    const float* __restrict__ H2, const int* __restrict__ rowPtr,
    const int* __restrict__ colA, const float* __restrict__ valA,
    const float* __restrict__ dinv, const float* __restrict__ b2,
    float* __restrict__ AG2) {
    int d = blockIdx.x, t = threadIdx.x;
    float self = dinv[d]; self *= self;
    const float* hd = H2 + (size_t)d * N2P;
    int f1 = t + 128;
    float a0 = self * hd[t];
    float a1 = self * hd[f1];          // H2 pad cols (>=250) are exact zeros
    int e0 = rowPtr[d], e1 = rowPtr[d + 1];
    for (int e = e0; e < e1; ++e) {
        int s = colA[e];
        float wv = valA[e];
        const float* hs = H2 + (size_t)s * N2P;
        a0 += wv * hs[t];
        a1 += wv * hs[f1];
    }
    float bb1 = (f1 < N2) ? b2[f1] : 0.f;
    AG2[(size_t)d * N2P + t]  = a0 + b2[t];
    AG2[(size_t)d * N2P + f1] = a1 + bb1;
}

// ---------------- heads: 34 dots of K=250 per node + softplus ----------------
__global__ __launch_bounds__(256) void heads(
    const float* __restrict__ AG2,
    const float* __restrict__ Wmt, const float* __restrict__ bmt,
    const float* __restrict__ Wst, const float* __restrict__ bst,
    const float* __restrict__ Wmz, const float* __restrict__ bmz,
    const float* __restrict__ Wsz, const float* __restrict__ bsz,
    float* __restrict__ out) {
    __shared__ float rows[4][N2P];
    int nb = blockIdx.x * 4, t = threadIdx.x;
#pragma unroll
    for (int j = 0; j < 4; j++) rows[j][t] = AG2[(size_t)(nb + j) * N2P + t];
    __syncthreads();
    if (t < 4 * 34) {
        int ni = t / 34, o = t - ni * 34;
        int node = nb + ni;
        const float* wp;
        float bias;
        int dosp = 1;
        size_t oidx;
        if (o == 0)      { wp = Wmt;                 bias = bmt[0];      oidx = (size_t)node; }
        else if (o == 1) { wp = Wst;                 bias = bst[0];      oidx = (size_t)N_NODES + node; }
        else if (o < 18) { wp = Wmz + (o - 2) * N2;  bias = bmz[o - 2];  oidx = (size_t)2 * N_NODES + (size_t)node * 16 + (o - 2);  dosp = 0; }
        else             { wp = Wsz + (o - 18) * N2; bias = bsz[o - 18]; oidx = (size_t)18 * N_NODES + (size_t)node * 16 + (o - 18); }
        float s = bias;
        for (int k = 0; k < N2; k++) s += rows[ni][k] * wp[k];
        if (dosp) s = fmaxf(s, 0.f) + log1pf(expf(-fabsf(s)));
        out[oidx] = s;
    }
}

extern "C" void kernel_launch(void* const* d_in, const int* in_sizes, int n_in,
                              void* d_out, int out_size, void* d_ws, size_t ws_size,
                              hipStream_t stream) {
    const float* X   = (const float*)d_in[0];
    const int*   EI  = (const int*)d_in[1];
    const float* EW  = (const float*)d_in[2];
    const float* W1  = (const float*)d_in[3];
    const float* b1  = (const float*)d_in[4];
    const float* W2  = (const float*)d_in[5];
    const float* b2  = (const float*)d_in[6];
    const float* Wmt = (const float*)d_in[7];
    const float* bmt = (const float*)d_in[8];
    const float* Wst = (const float*)d_in[9];
    const float* bst = (const float*)d_in[10];
    const float* Wmz = (const float*)d_in[11];
    const float* bmz = (const float*)d_in[12];
    const float* Wsz = (const float*)d_in[13];
    const float* bsz = (const float*)d_in[14];
    float* out = (float*)d_out;

    char* ws = (char*)d_ws;
    size_t off = 0;
    auto alloc = [&](size_t bytes) -> char* {
        char* p = ws + off;
        off += (bytes + 255) & ~(size_t)255;
        return p;
    };
    unsigned short* Xb  = (unsigned short*)alloc((size_t)N_NODES * KP1 * 2);
    unsigned short* W1b = (unsigned short*)alloc((size_t)N1P * KP1 * 2);
    float*          H1  = (float*)alloc((size_t)N_NODES * N1P * 4);
    unsigned short* AG1 = (unsigned short*)alloc((size_t)N_NODES * N1P * 2);
    unsigned short* W2b = (unsigned short*)alloc((size_t)N2P * N1P * 2);
    float*          H2  = (float*)alloc((size_t)N_NODES * N2P * 4);
    float*          AG2 = (float*)alloc((size_t)N_NODES * N2P * 4);
    float* deg    = (float*)alloc(N_NODES * 4);
    float* dinv   = (float*)alloc(N_NODES * 4);
    int*   cnt    = (int*)alloc(N_NODES * 4);
    int*   cursor = (int*)alloc(N_NODES * 4);
    int*   rowPtr = (int*)alloc((N_NODES + 1) * 4);
    int*   colA   = (int*)alloc(N_EDGES * 4);
    float* valA   = (float*)alloc(N_EDGES * 4);
    if (off > ws_size) return;   // loud failure: d_out stays poisoned

    // graph prep
    k_init<<<(N_NODES + 255) / 256, 256, 0, stream>>>(deg, cnt, cursor);
    k_count<<<(N_EDGES + 255) / 256, 256, 0, stream>>>(EI, EW, deg, cnt);
    k_dinv<<<(N_NODES + 255) / 256, 256, 0, stream>>>(deg, dinv);
    scan_kernel<<<1, 1024, 0, stream>>>(cnt, rowPtr);
    k_fill<<<(N_EDGES + 255) / 256, 256, 0, stream>>>(EI, EW, dinv, rowPtr, cursor, colA, valA);

    // bf16 conversions (padded)
    conv_x<<<(N_NODES * (KP1 / 2) + 255) / 256, 256, 0, stream>>>(X, (unsigned int*)Xb);
    conv_w<<<(N1P * (KP1 / 2) + 255) / 256, 256, 0, stream>>>(W1, (unsigned int*)W1b,
                                                              N1P * (KP1 / 2), N1, CIN, KP1 / 2);
    conv_w<<<(N2P * (N1P / 2) + 255) / 256, 256, 0, stream>>>(W2, (unsigned int*)W2b,
                                                              N2P * (N1P / 2), N2, N1, N1P / 2);

    // layer 1
    gemm_bt<<<dim3(N1P / 128, (N_NODES + 127) / 128), 256, 0, stream>>>(
        Xb, W1b, H1, N_NODES, KP1, KP1, N1P, KP1 / 32);
    agg1<<<N_NODES, 256, 0, stream>>>(H1, rowPtr, colA, valA, dinv, b1, AG1);

    // layer 2
    gemm_bt<<<dim3(N2P / 128, (N_NODES + 127) / 128), 256, 0, stream>>>(
        AG1, W2b, H2, N_NODES, N1P, N1P, N2P, N1P / 32);
    agg2<<<N_NODES, 128, 0, stream>>>(H2, rowPtr, colA, valA, dinv, b2, AG2);

    // heads
    heads<<<N_NODES / 4, 256, 0, stream>>>(AG2, Wmt, bmt, Wst, bst, Wmz, bmz, Wsz, bsz, out);
}

// Round 2
// 324.451 us; speedup vs baseline: 1.1448x; 1.1448x over previous
//
#include <hip/hip_runtime.h>

#define N_NODES 20000
#define N_EDGES 160000
#define CIN     2000
#define KP1     2048   // CIN padded to mult of 32
#define N1      500
#define N1P     512
#define N2      250
#define N2P     256

typedef __attribute__((ext_vector_type(4))) float f32x4;
typedef __attribute__((ext_vector_type(8))) __bf16 bf16x8;
typedef __attribute__((ext_vector_type(8))) unsigned short ushort8;

typedef const __attribute__((address_space(1))) void* as1cv;
typedef __attribute__((address_space(3))) void* as3v;

__device__ __forceinline__ unsigned short f2bf(float f) {
    unsigned int u = __builtin_bit_cast(unsigned int, f);
    u += 0x7FFFu + ((u >> 16) & 1u);   // RNE
    return (unsigned short)(u >> 16);
}
__device__ __forceinline__ float bf2f(unsigned short h) {
    unsigned int u = ((unsigned int)h) << 16;
    return __builtin_bit_cast(float, u);
}

// ---------------- graph prep ----------------
__global__ void k_init(float* deg, int* cnt, int* cursor) {
    int i = blockIdx.x * 256 + threadIdx.x;
    if (i < N_NODES) { deg[i] = 1.0f; cnt[i] = 0; cursor[i] = 0; }
}

__global__ void k_count(const int* __restrict__ ei, const float* __restrict__ ew,
                        float* deg, int* cnt) {
    int e = blockIdx.x * 256 + threadIdx.x;
    if (e < N_EDGES) {
        int d = ei[N_EDGES + e];
        atomicAdd(&deg[d], ew[e]);
        atomicAdd(&cnt[d], 1);
    }
}

// exclusive scan of cnt -> rowPtr, fused with dinv = rsqrt(deg)
__global__ void scan_dinv(const int* __restrict__ cnt, const float* __restrict__ deg,
                          float* __restrict__ dinv, int* __restrict__ rowPtr) {
    __shared__ int buf[1024];
    __shared__ int carry;
    int t = threadIdx.x;
    if (t == 0) { carry = 0; rowPtr[0] = 0; }
    __syncthreads();
    for (int base = 0; base < N_NODES; base += 1024) {
        int i = base + t;
        int v = 0;
        if (i < N_NODES) { v = cnt[i]; dinv[i] = rsqrtf(deg[i]); }
        buf[t] = v;
        __syncthreads();
        for (int off = 1; off < 1024; off <<= 1) {
            int x = (t >= off) ? buf[t - off] : 0;
            __syncthreads();
            buf[t] += x;
            __syncthreads();
        }
        int inc = buf[t] + carry;
        if (i < N_NODES) rowPtr[i + 1] = inc;
        __syncthreads();
        if (t == 1023) carry = inc;
        __syncthreads();
    }
}

__global__ void k_fill(const int* __restrict__ ei, const float* __restrict__ ew,
                       const float* __restrict__ dinv, const int* __restrict__ rowPtr,
                       int* cursor, int* __restrict__ colA, float* __restrict__ valA) {
    int e = blockIdx.x * 256 + threadIdx.x;
    if (e < N_EDGES) {
        int s = ei[e], d = ei[N_EDGES + e];
        int p = atomicAdd(&cursor[d], 1);
        int j = rowPtr[d] + p;
        colA[j] = s;
        valA[j] = dinv[s] * ew[e] * dinv[d];
    }
}

// ---------------- f32 -> bf16 conversion (padded) ----------------
__global__ void conv_x(const float* __restrict__ X, uint2* __restrict__ Xb) {
    int idx = blockIdx.x * 256 + threadIdx.x;       // quad index; 512 quads/row
    if (idx >= N_NODES * (KP1 / 4)) return;
    int m = idx >> 9, c = idx & 511;
    int k = c * 4;
    uint2 o = {0u, 0u};
    if (k < CIN) {   // CIN%4==0: quads are all-in or all-pad
        float4 v = *reinterpret_cast<const float4*>(X + (size_t)m * CIN + k);
        o.x = (unsigned int)f2bf(v.x) | ((unsigned int)f2bf(v.y) << 16);
        o.y = (unsigned int)f2bf(v.z) | ((unsigned int)f2bf(v.w) << 16);
    }
    Xb[idx] = o;
}

// both weight matrices in one launch
__global__ void conv_w(const float* __restrict__ W1, const float* __restrict__ W2,
                       unsigned int* __restrict__ W1b, unsigned int* __restrict__ W2b) {
    const int T1 = N1P * (KP1 / 2);   // 524288 pairs
    const int T2 = N2P * (N1P / 2);   // 65536 pairs
    int idx = blockIdx.x * 256 + threadIdx.x;
    if (idx < T1) {
        int r = idx >> 10, c = idx & 1023;
        int k = c * 2;
        unsigned int o = 0;
        if (r < N1 && k < CIN) {
            float2 v = *reinterpret_cast<const float2*>(W1 + (size_t)r * CIN + k);
            o = (unsigned int)f2bf(v.x) | ((unsigned int)f2bf(v.y) << 16);
        }
        W1b[idx] = o;
    } else if (idx < T1 + T2) {
        int j = idx - T1;
        int r = j >> 8, c = j & 255;
        int k = c * 2;
        unsigned int o = 0;
        if (r < N2 && k < N1) {
            float2 v = *reinterpret_cast<const float2*>(W2 + (size_t)r * N1 + k);
            o = (unsigned int)f2bf(v.x) | ((unsigned int)f2bf(v.y) << 16);
        }
        W2b[j] = o;
    }
}

// ---------------- bf16 MFMA GEMM: C[M,N] = A[M,K] * B[N,K]^T ----------------
// A,B bf16 row-major K-contiguous. 128x128 tile, BK=32, 4 waves, 16x16x32 MFMA,
// global_load_lds staging, bijective XCD swizzle (m204). OutT = float | ushort(bf16).
template <typename OutT>
__global__ __launch_bounds__(256) void gemm_bt(
    const unsigned short* __restrict__ A, const unsigned short* __restrict__ B,
    OutT* __restrict__ C, int M, int lda, int ldb, int ldc, int nk) {
    __shared__ alignas(16) unsigned short lA[128 * 32];
    __shared__ alignas(16) unsigned short lB[128 * 32];
    const int t = threadIdx.x;
    const int w = t >> 6, lane = t & 63;

    // XCD-aware bijective swizzle: contiguous logical ids per XCD
    const int nwg = gridDim.x * gridDim.y;
    const int orig = blockIdx.y * gridDim.x + blockIdx.x;
    const int q = nwg >> 3, r = nwg & 7;
    const int xcd = orig & 7, loc = orig >> 3;
    const int wg = (xcd < r ? xcd * (q + 1) : r * (q + 1) + (xcd - r) * q) + loc;
    const int bn0 = (wg % gridDim.x) * 128;
    const int bm0 = (wg / gridDim.x) * 128;

    const int wr = w >> 1, wc = w & 1;               // wave -> 64x64 quadrant
    const int lr = lane & 15, lk = (lane >> 4) * 8;  // fragment row / k-offset

    f32x4 acc[4][4];
#pragma unroll
    for (int i = 0; i < 4; i++)
#pragma unroll
        for (int j = 0; j < 4; j++) acc[i][j] = (f32x4){0.f, 0.f, 0.f, 0.f};

    for (int kt = 0; kt < nk; ++kt) {
        const int kb = kt * 32;
#pragma unroll
        for (int i = 0; i < 2; i++) {
            int c0 = i * 256 + w * 64;
            int c  = c0 + lane;
            int rr = c >> 2, kg = c & 3;
            int grow = bm0 + rr; grow = grow < M ? grow : M - 1;
            const unsigned short* gp = A + (size_t)grow * lda + kb + kg * 8;
            __builtin_amdgcn_global_load_lds((as1cv)gp, (as3v)(lA + (size_t)c0 * 8), 16, 0, 0);
        }
#pragma unroll
        for (int i = 0; i < 2; i++) {
            int c0 = i * 256 + w * 64;
            int c  = c0 + lane;
            int rr = c >> 2, kg = c & 3;
            const unsigned short* gp = B + (size_t)(bn0 + rr) * ldb + kb + kg * 8;
            __builtin_amdgcn_global_load_lds((as1cv)gp, (as3v)(lB + (size_t)c0 * 8), 16, 0, 0);
        }
        __syncthreads();
        ushort8 af[4], bfr[4];
#pragma unroll
        for (int m = 0; m < 4; m++)
            af[m] = *reinterpret_cast<const ushort8*>(&lA[(wr * 64 + m * 16 + lr) * 32 + lk]);
#pragma unroll
        for (int n = 0; n < 4; n++)
            bfr[n] = *reinterpret_cast<const ushort8*>(&lB[(wc * 64 + n * 16 + lr) * 32 + lk]);
#pragma unroll
        for (int m = 0; m < 4; m++)
#pragma unroll
            for (int n = 0; n < 4; n++)
                acc[m][n] = __builtin_amdgcn_mfma_f32_16x16x32_bf16(
                    __builtin_bit_cast(bf16x8, af[m]), __builtin_bit_cast(bf16x8, bfr[n]),
                    acc[m][n], 0, 0, 0);
        __syncthreads();
    }
    // epilogue: C/D layout col = lane&15, row = (lane>>4)*4 + reg   [m89-verified]
    const int crow0 = bm0 + wr * 64 + (lane >> 4) * 4;
    const int ccol0 = bn0 + wc * 64 + lr;
#pragma unroll
    for (int m = 0; m < 4; m++)
#pragma unroll
        for (int n = 0; n < 4; n++)
#pragma unroll
            for (int rg = 0; rg < 4; rg++) {
                int row = crow0 + m * 16 + rg;
                if (row < M) {
                    float v = acc[m][n][rg];
                    if constexpr (__is_same(OutT, unsigned short))
                        C[(size_t)row * ldc + ccol0 + n * 16] = f2bf(v);
                    else
                        C[(size_t)row * ldc + ccol0 + n * 16] = v;
                }
            }
}

// ---------------- aggregation 1: AG1 = A_hat @ H1(bf16) + b1, bf16 out ----------------
// thread t owns features 2t, 2t+1 (one dword per row). Edge list staged in LDS,
// 4-way unrolled independent gathers for MLP (memory-level parallelism).
__global__ __launch_bounds__(256) void agg1(
    const unsigned short* __restrict__ H1b, const int* __restrict__ rowPtr,
    const int* __restrict__ colA, const float* __restrict__ valA,
    const float* __restrict__ dinv, const float* __restrict__ b1,
    unsigned int* __restrict__ AG1) {
    __shared__ int scol[256];
    __shared__ float sval[256];
    const unsigned int* H = (const unsigned int*)H1b;   // 256 dwords/row
    int d = blockIdx.x, t = threadIdx.x;
    float self = dinv[d]; self *= self;
    unsigned int su = H[(size_t)d * 256 + t];
    float a0 = self * bf2f((unsigned short)su);
    float a1 = self * bf2f((unsigned short)(su >> 16));
    int e0 = rowPtr[d], e1 = rowPtr[d + 1];
    for (int base = e0; base < e1; base += 256) {
        int n = e1 - base; if (n > 256) n = 256;
        if (t < n) { scol[t] = colA[base + t]; sval[t] = valA[base + t]; }
        __syncthreads();
        int i = 0;
        for (; i + 4 <= n; i += 4) {
            int s0 = scol[i], s1 = scol[i + 1], s2 = scol[i + 2], s3 = scol[i + 3];
            float w0 = sval[i], w1 = sval[i + 1], w2 = sval[i + 2], w3 = sval[i + 3];
            unsigned int u0 = H[(size_t)s0 * 256 + t];
            unsigned int u1 = H[(size_t)s1 * 256 + t];
            unsigned int u2 = H[(size_t)s2 * 256 + t];
            unsigned int u3 = H[(size_t)s3 * 256 + t];
            a0 += w0 * bf2f((unsigned short)u0) + w1 * bf2f((unsigned short)u1)
                + w2 * bf2f((unsigned short)u2) + w3 * bf2f((unsigned short)u3);
            a1 += w0 * bf2f((unsigned short)(u0 >> 16)) + w1 * bf2f((unsigned short)(u1 >> 16))
                + w2 * bf2f((unsigned short)(u2 >> 16)) + w3 * bf2f((unsigned short)(u3 >> 16));
        }
        for (; i < n; ++i) {
            int s = scol[i]; float w = sval[i];
            unsigned int u = H[(size_t)s * 256 + t];
            a0 += w * bf2f((unsigned short)u);
            a1 += w * bf2f((unsigned short)(u >> 16));
        }
        __syncthreads();
    }
    int f = 2 * t;
    float r0 = (f < N1) ? a0 + b1[f] : 0.f;
    float r1 = (f + 1 < N1) ? a1 + b1[f + 1] : 0.f;
    AG1[(size_t)d * 256 + t] = (unsigned int)f2bf(r0) | ((unsigned int)f2bf(r1) << 16);
}

// ---------------- aggregation 2: AG2 = A_hat @ H2(f32) + b2, f32 out ----------------
__global__ __launch_bounds__(128) void agg2(
    const float* __restrict__ H2, const int* __restrict__ rowPtr,
    const int* __restrict__ colA, const float* __restrict__ valA,
    const float* __restrict__ dinv, const float* __restrict__ b2,
    float* __restrict__ AG2) {
    __shared__ int scol[128];
    __shared__ float sval[128];
    int d = blockIdx.x, t = threadIdx.x;
    float self = dinv[d]; self *= self;
    float2 h = *reinterpret_cast<const float2*>(H2 + (size_t)d * N2P + 2 * t);
    float a0 = self * h.x, a1 = self * h.y;
    int e0 = rowPtr[d], e1 = rowPtr[d + 1];
    for (int base = e0; base < e1; base += 128) {
        int n = e1 - base; if (n > 128) n = 128;
        if (t < n) { scol[t] = colA[base + t]; sval[t] = valA[base + t]; }
        __syncthreads();
        int i = 0;
        for (; i + 4 <= n; i += 4) {
            int s0 = scol[i], s1 = scol[i + 1], s2 = scol[i + 2], s3 = scol[i + 3];
            float w0 = sval[i], w1 = sval[i + 1], w2 = sval[i + 2], w3 = sval[i + 3];
            float2 h0 = *reinterpret_cast<const float2*>(H2 + (size_t)s0 * N2P + 2 * t);
            float2 h1 = *reinterpret_cast<const float2*>(H2 + (size_t)s1 * N2P + 2 * t);
            float2 h2 = *reinterpret_cast<const float2*>(H2 + (size_t)s2 * N2P + 2 * t);
            float2 h3 = *reinterpret_cast<const float2*>(H2 + (size_t)s3 * N2P + 2 * t);
            a0 += w0 * h0.x + w1 * h1.x + w2 * h2.x + w3 * h3.x;
            a1 += w0 * h0.y + w1 * h1.y + w2 * h2.y + w3 * h3.y;
        }
        for (; i < n; ++i) {
            int s = scol[i]; float w = sval[i];
            float2 hh = *reinterpret_cast<const float2*>(H2 + (size_t)s * N2P + 2 * t);
            a0 += w * hh.x;
            a1 += w * hh.y;
        }
        __syncthreads();
    }
    int f = 2 * t;
    float r0 = (f < N2) ? a0 + b2[f] : 0.f;
    float r1 = (f + 1 < N2) ? a1 + b2[f + 1] : 0.f;
    *reinterpret_cast<float2*>(AG2 + (size_t)d * N2P + 2 * t) = make_float2(r0, r1);
}

// ---------------- heads: 34 dots of K=250 per node + softplus ----------------
__global__ __launch_bounds__(256) void heads(
    const float* __restrict__ AG2,
    const float* __restrict__ Wmt, const float* __restrict__ bmt,
    const float* __restrict__ Wst, const float* __restrict__ bst,
    const float* __restrict__ Wmz, const float* __restrict__ bmz,
    const float* __restrict__ Wsz, const float* __restrict__ bsz,
    float* __restrict__ out) {
    __shared__ float rows[4][N2P];
    int nb = blockIdx.x * 4, t = threadIdx.x;
#pragma unroll
    for (int j = 0; j < 4; j++) rows[j][t] = AG2[(size_t)(nb + j) * N2P + t];
    __syncthreads();
    if (t < 4 * 34) {
        int ni = t / 34, o = t - ni * 34;
        int node = nb + ni;
        const float* wp;
        float bias;
        int dosp = 1;
        size_t oidx;
        if (o == 0)      { wp = Wmt;                 bias = bmt[0];      oidx = (size_t)node; }
        else if (o == 1) { wp = Wst;                 bias = bst[0];      oidx = (size_t)N_NODES + node; }
        else if (o < 18) { wp = Wmz + (o - 2) * N2;  bias = bmz[o - 2];  oidx = (size_t)2 * N_NODES + (size_t)node * 16 + (o - 2);  dosp = 0; }
        else             { wp = Wsz + (o - 18) * N2; bias = bsz[o - 18]; oidx = (size_t)18 * N_NODES + (size_t)node * 16 + (o - 18); }
        float s = bias;
        for (int k = 0; k < N2; k++) s += rows[ni][k] * wp[k];
        if (dosp) s = fmaxf(s, 0.f) + log1pf(expf(-fabsf(s)));
        out[oidx] = s;
    }
}

extern "C" void kernel_launch(void* const* d_in, const int* in_sizes, int n_in,
                              void* d_out, int out_size, void* d_ws, size_t ws_size,
                              hipStream_t stream) {
    const float* X   = (const float*)d_in[0];
    const int*   EI  = (const int*)d_in[1];
    const float* EW  = (const float*)d_in[2];
    const float* W1  = (const float*)d_in[3];
    const float* b1  = (const float*)d_in[4];
    const float* W2  = (const float*)d_in[5];
    const float* b2  = (const float*)d_in[6];
    const float* Wmt = (const float*)d_in[7];
    const float* bmt = (const float*)d_in[8];
    const float* Wst = (const float*)d_in[9];
    const float* bst = (const float*)d_in[10];
    const float* Wmz = (const float*)d_in[11];
    const float* bmz = (const float*)d_in[12];
    const float* Wsz = (const float*)d_in[13];
    const float* bsz = (const float*)d_in[14];
    float* out = (float*)d_out;

    char* ws = (char*)d_ws;
    size_t off = 0;
    auto alloc = [&](size_t bytes) -> char* {
        char* p = ws + off;
        off += (bytes + 255) & ~(size_t)255;
        return p;
    };
    unsigned short* Xb  = (unsigned short*)alloc((size_t)N_NODES * KP1 * 2);
    unsigned short* W1b = (unsigned short*)alloc((size_t)N1P * KP1 * 2);
    unsigned short* H1b = (unsigned short*)alloc((size_t)N_NODES * N1P * 2);   // bf16 now
    unsigned int*   AG1 = (unsigned int*)alloc((size_t)N_NODES * N1P * 2);
    unsigned short* W2b = (unsigned short*)alloc((size_t)N2P * N1P * 2);
    float*          H2  = (float*)alloc((size_t)N_NODES * N2P * 4);
    float*          AG2 = (float*)alloc((size_t)N_NODES * N2P * 4);
    float* deg    = (float*)alloc(N_NODES * 4);
    float* dinv   = (float*)alloc(N_NODES * 4);
    int*   cnt    = (int*)alloc(N_NODES * 4);
    int*   cursor = (int*)alloc(N_NODES * 4);
    int*   rowPtr = (int*)alloc((N_NODES + 1) * 4);
    int*   colA   = (int*)alloc(N_EDGES * 4);
    float* valA   = (float*)alloc(N_EDGES * 4);
    if (off > ws_size) return;   // loud failure: d_out stays poisoned

    // graph prep (4 launches)
    k_init<<<(N_NODES + 255) / 256, 256, 0, stream>>>(deg, cnt, cursor);
    k_count<<<(N_EDGES + 255) / 256, 256, 0, stream>>>(EI, EW, deg, cnt);
    scan_dinv<<<1, 1024, 0, stream>>>(cnt, deg, dinv, rowPtr);
    k_fill<<<(N_EDGES + 255) / 256, 256, 0, stream>>>(EI, EW, dinv, rowPtr, cursor, colA, valA);

    // bf16 conversions (2 launches)
    conv_x<<<(N_NODES * (KP1 / 4) + 255) / 256, 256, 0, stream>>>(X, (uint2*)Xb);
    {
        int total = N1P * (KP1 / 2) + N2P * (N1P / 2);
        conv_w<<<(total + 255) / 256, 256, 0, stream>>>(W1, W2, (unsigned int*)W1b,
                                                        (unsigned int*)W2b);
    }

    // layer 1
    gemm_bt<unsigned short><<<dim3(N1P / 128, (N_NODES + 127) / 128), 256, 0, stream>>>(
        Xb, W1b, H1b, N_NODES, KP1, KP1, N1P, KP1 / 32);
    agg1<<<N_NODES, 256, 0, stream>>>(H1b, rowPtr, colA, valA, dinv, b1, AG1);

    // layer 2
    gemm_bt<float><<<dim3(N2P / 128, (N_NODES + 127) / 128), 256, 0, stream>>>(
        (const unsigned short*)AG1, W2b, H2, N_NODES, N1P, N1P, N2P, N1P / 32);
    agg2<<<N_NODES, 128, 0, stream>>>(H2, rowPtr, colA, valA, dinv, b2, AG2);

    // heads
    heads<<<N_NODES / 4, 256, 0, stream>>>(AG2, Wmt, bmt, Wst, bst, Wmz, bmz, Wsz, bsz, out);
}

// Round 3
// 193.872 us; speedup vs baseline: 1.9158x; 1.6735x over previous
//
#include <hip/hip_runtime.h>

#define N_NODES 20000
#define N_EDGES 160000
#define CIN     2000
#define N1      500
#define N2      250
#define NH      34     // heads: 1 + 1 + 16 + 16
#define NHP     64

typedef __attribute__((ext_vector_type(4))) float f32x4;
typedef __attribute__((ext_vector_type(8))) __bf16 bf16x8;
typedef __attribute__((ext_vector_type(8))) unsigned short ushort8;

typedef const __attribute__((address_space(1))) void* as1cv;
typedef __attribute__((address_space(3))) void* as3v;

__device__ __forceinline__ unsigned short f2bf(float f) {
    unsigned int u = __builtin_bit_cast(unsigned int, f);
    u += 0x7FFFu + ((u >> 16) & 1u);   // RNE
    return (unsigned short)(u >> 16);
}

__device__ __forceinline__ ushort8 pack8(float4 a, float4 b) {
    ushort8 r;
    r[0] = f2bf(a.x); r[1] = f2bf(a.y); r[2] = f2bf(a.z); r[3] = f2bf(a.w);
    r[4] = f2bf(b.x); r[5] = f2bf(b.y); r[6] = f2bf(b.z); r[7] = f2bf(b.w);
    return r;
}

// ---------------- graph prep ----------------
__global__ void k_init(float* deg, int* cnt, int* cursor) {
    int i = blockIdx.x * 256 + threadIdx.x;
    if (i < N_NODES) { deg[i] = 1.0f; cnt[i] = 0; cursor[i] = 0; }
}

__global__ void k_count(const int* __restrict__ ei, const float* __restrict__ ew,
                        float* deg, int* cnt) {
    int e = blockIdx.x * 256 + threadIdx.x;
    if (e < N_EDGES) {
        int d = ei[N_EDGES + e];
        atomicAdd(&deg[d], ew[e]);
        atomicAdd(&cnt[d], 1);
    }
}

// single-pass scan: thread owns 20 elements; one 1024-wide block scan (10 rounds)
__global__ void scan_dinv(const int* __restrict__ cnt, const float* __restrict__ deg,
                          float* __restrict__ dinv, int* __restrict__ rowPtr) {
    __shared__ int partial[1024];
    int t = threadIdx.x;
    int base = t * 20;
    int loc[20]; int s = 0;
#pragma unroll
    for (int i = 0; i < 20; ++i) {
        int idx = base + i;
        int v = 0;
        if (idx < N_NODES) { v = cnt[idx]; dinv[idx] = rsqrtf(deg[idx]); }
        loc[i] = s; s += v;
    }
    partial[t] = s;
    __syncthreads();
    for (int off = 1; off < 1024; off <<= 1) {
        int x = (t >= off) ? partial[t - off] : 0;
        __syncthreads();
        partial[t] += x;
        __syncthreads();
    }
    int pre = (t == 0) ? 0 : partial[t - 1];
#pragma unroll
    for (int i = 0; i < 20; ++i) {
        int idx = base + i;
        if (idx < N_NODES) rowPtr[idx] = pre + loc[i];
    }
    if (t == 1023) rowPtr[N_NODES] = partial[1023];
}

__global__ void k_fill(const int* __restrict__ ei, const float* __restrict__ ew,
                       const float* __restrict__ dinv, const int* __restrict__ rowPtr,
                       int* cursor, int* __restrict__ colA, float* __restrict__ valA) {
    int e = blockIdx.x * 256 + threadIdx.x;
    if (e < N_EDGES) {
        int s = ei[e], d = ei[N_EDGES + e];
        int p = atomicAdd(&cursor[d], 1);
        int j = rowPtr[d] + p;
        colA[j] = s;
        valA[j] = dinv[s] * ew[e] * dinv[d];
    }
}

// ---------------- weight prep: W2 -> bf16 [256][512]; W1 -> transposed bf16 [2048][512] ----------------
__global__ void prep_w(const float* __restrict__ W2, const float* __restrict__ W1,
                       unsigned int* __restrict__ W2b, unsigned short* __restrict__ W1T) {
    int b = blockIdx.x, t = threadIdx.x;
    if (b < 256) {           // W2b: 65536 dwords
        int idx = b * 256 + t;
        int r = idx >> 8, c = idx & 255;
        int k = c * 2;
        unsigned int o = 0;
        if (r < N2 && k < N1) {
            float2 v = *reinterpret_cast<const float2*>(W2 + (size_t)r * N1 + k);
            o = (unsigned int)f2bf(v.x) | ((unsigned int)f2bf(v.y) << 16);
        }
        W2b[idx] = o;
    } else {                 // transpose W1 [500][2000] -> W1T bf16 [2048][512]
        __shared__ float tile[32][33];
        int bb = b - 256;                 // 0..1023
        int jt = bb & 15, nt = bb >> 4;   // 16 j-tiles x 64 n-tiles
        int c = t & 31, r = t >> 5;       // 8 rows/pass
#pragma unroll
        for (int i = 0; i < 4; ++i) {
            int j = jt * 32 + r + i * 8;
            int n = nt * 32 + c;
            tile[r + i * 8][c] = (j < N1 && n < CIN) ? W1[(size_t)j * CIN + n] : 0.f;
        }
        __syncthreads();
#pragma unroll
        for (int i = 0; i < 4; ++i) {
            int n = nt * 32 + r + i * 8;   // output row
            int j = jt * 32 + c;           // output col
            W1T[(size_t)n * 512 + j] = f2bf(tile[c][r + i * 8]);
        }
    }
}

// ---------------- bf16 MFMA GEMM (m97-style): C[M,N] = A[M,K] * B[N,K]^T ----------------
template <typename OutT>
__global__ __launch_bounds__(256) void gemm_bt(
    const unsigned short* __restrict__ A, const unsigned short* __restrict__ B,
    OutT* __restrict__ C, int M, int lda, int ldb, int ldc, int nk) {
    __shared__ alignas(16) unsigned short lA[128 * 32];
    __shared__ alignas(16) unsigned short lB[128 * 32];
    const int t = threadIdx.x;
    const int w = t >> 6, lane = t & 63;
    const int nwg = gridDim.x * gridDim.y;
    const int orig = blockIdx.y * gridDim.x + blockIdx.x;
    const int q = nwg >> 3, r = nwg & 7;
    const int xcd = orig & 7, loc = orig >> 3;
    const int wg = (xcd < r ? xcd * (q + 1) : r * (q + 1) + (xcd - r) * q) + loc;
    const int bn0 = (wg % gridDim.x) * 128;
    const int bm0 = (wg / gridDim.x) * 128;
    const int wr = w >> 1, wc = w & 1;
    const int lr = lane & 15, lk = (lane >> 4) * 8;

    f32x4 acc[4][4];
#pragma unroll
    for (int i = 0; i < 4; i++)
#pragma unroll
        for (int j = 0; j < 4; j++) acc[i][j] = (f32x4){0.f, 0.f, 0.f, 0.f};

    for (int kt = 0; kt < nk; ++kt) {
        const int kb = kt * 32;
#pragma unroll
        for (int i = 0; i < 2; i++) {
            int c0 = i * 256 + w * 64;
            int c  = c0 + lane;
            int rr = c >> 2, kg = c & 3;
            int grow = bm0 + rr; grow = grow < M ? grow : M - 1;
            const unsigned short* gp = A + (size_t)grow * lda + kb + kg * 8;
            __builtin_amdgcn_global_load_lds((as1cv)gp, (as3v)(lA + (size_t)c0 * 8), 16, 0, 0);
        }
#pragma unroll
        for (int i = 0; i < 2; i++) {
            int c0 = i * 256 + w * 64;
            int c  = c0 + lane;
            int rr = c >> 2, kg = c & 3;
            const unsigned short* gp = B + (size_t)(bn0 + rr) * ldb + kb + kg * 8;
            __builtin_amdgcn_global_load_lds((as1cv)gp, (as3v)(lB + (size_t)c0 * 8), 16, 0, 0);
        }
        __syncthreads();
        ushort8 af[4], bfr[4];
#pragma unroll
        for (int m = 0; m < 4; m++)
            af[m] = *reinterpret_cast<const ushort8*>(&lA[(wr * 64 + m * 16 + lr) * 32 + lk]);
#pragma unroll
        for (int n = 0; n < 4; n++)
            bfr[n] = *reinterpret_cast<const ushort8*>(&lB[(wc * 64 + n * 16 + lr) * 32 + lk]);
#pragma unroll
        for (int m = 0; m < 4; m++)
#pragma unroll
            for (int n = 0; n < 4; n++)
                acc[m][n] = __builtin_amdgcn_mfma_f32_16x16x32_bf16(
                    __builtin_bit_cast(bf16x8, af[m]), __builtin_bit_cast(bf16x8, bfr[n]),
                    acc[m][n], 0, 0, 0);
        __syncthreads();
    }
    const int crow0 = bm0 + wr * 64 + (lane >> 4) * 4;
    const int ccol0 = bn0 + wc * 64 + lr;
#pragma unroll
    for (int m = 0; m < 4; m++)
#pragma unroll
        for (int n = 0; n < 4; n++)
#pragma unroll
            for (int rg = 0; rg < 4; rg++) {
                int row = crow0 + m * 16 + rg;
                if (row < M) {
                    float v = acc[m][n][rg];
                    if constexpr (__is_same(OutT, unsigned short))
                        C[(size_t)row * ldc + ccol0 + n * 16] = f2bf(v);
                    else
                        C[(size_t)row * ldc + ccol0 + n * 16] = v;
                }
            }
}

// ---------------- cc = Wh W2 b1, dd = Wh b2 + bh  (single block) ----------------
__global__ void small_vec(const float* __restrict__ W2, const float* __restrict__ b1,
                          const float* __restrict__ b2,
                          const float* __restrict__ Wmt, const float* __restrict__ bmt,
                          const float* __restrict__ Wst, const float* __restrict__ bst,
                          const float* __restrict__ Wmz, const float* __restrict__ bmz,
                          const float* __restrict__ Wsz, const float* __restrict__ bsz,
                          float* __restrict__ ccdd) {
    __shared__ float c1[256];
    int t = threadIdx.x;
    float a = 0.f;
    if (t < N2) {
        for (int j = 0; j < N1; ++j) a += W2[(size_t)t * N1 + j] * b1[j];
    }
    c1[t] = (t < N2) ? a : 0.f;
    __syncthreads();
    if (t < NHP) {
        float cc = 0.f, dv = 0.f;
        if (t < NH) {
            const float* src; int row; float bias;
            if (t == 0)      { src = Wmt; row = 0;      bias = bmt[0]; }
            else if (t == 1) { src = Wst; row = 0;      bias = bst[0]; }
            else if (t < 18) { src = Wmz; row = t - 2;  bias = bmz[t - 2]; }
            else             { src = Wsz; row = t - 18; bias = bsz[t - 18]; }
            dv = bias;
            for (int j = 0; j < N2; ++j) {
                float wv = src[(size_t)row * N2 + j];
                cc += wv * c1[j];
                dv += wv * b2[j];
            }
        }
        ccdd[t] = cc;
        ccdd[NHP + t] = dv;
    }
}

// ---------------- Wt[o][n] = sum_j Wh[o][j] * W21f[j][n]  -> bf16 [64][2048] ----------------
__global__ __launch_bounds__(256) void wt_build(
    const float* __restrict__ W21f,
    const float* __restrict__ Wmt, const float* __restrict__ Wst,
    const float* __restrict__ Wmz, const float* __restrict__ Wsz,
    unsigned short* __restrict__ Wtb) {
    __shared__ float wh[256];
    int o = blockIdx.y, t = threadIdx.x;
    int n = blockIdx.x * 256 + t;
    const float* src = Wmt; int row = 0; bool valid = (o < NH);
    if (o == 1)            { src = Wst; row = 0; }
    else if (o >= 2 && o < 18)  { src = Wmz; row = o - 2; }
    else if (o >= 18 && o < 34) { src = Wsz; row = o - 18; }
    wh[t] = (valid && t < N2) ? src[(size_t)row * N2 + t] : 0.f;
    __syncthreads();
    float acc = 0.f;
    if (valid && n < CIN) {
        for (int j = 0; j < N2; ++j) acc += wh[j] * W21f[(size_t)j * 2048 + n];
    }
    Wtb[(size_t)o * 2048 + n] = f2bf(acc);
}

// ---------------- the one big GEMM: Tpart[kp] = X(f32,cvt) @ Wt^T, N=64, split-K x2 ----------------
__global__ __launch_bounds__(256) void gemm_T(
    const float* __restrict__ X, const unsigned short* __restrict__ Wtb,
    float* __restrict__ Tpart) {
    __shared__ alignas(16) unsigned short lA[64 * 64];
    __shared__ alignas(16) unsigned short lB[64 * 64];
    const int t = threadIdx.x, w = t >> 6, lane = t & 63;
    const int kp = blockIdx.x;          // 0,1
    const int bm0 = blockIdx.y * 64;
    const int kbase = kp * 1024;
    const int lr = lane & 15, lkb = (lane >> 4) * 16;

    // staging: 512 chunks of 8 elems; thread owns chunks t and t+256
    const int c0 = t, c1 = t + 256;
    const int ar0 = c0 >> 3, ac0 = (c0 & 7) * 8;
    const int ar1 = c1 >> 3, ac1 = (c1 & 7) * 8;
    int gr0 = bm0 + ar0; if (gr0 >= N_NODES) gr0 = N_NODES - 1;
    int gr1 = bm0 + ar1; if (gr1 >= N_NODES) gr1 = N_NODES - 1;
    const float* pA0 = X + (size_t)gr0 * CIN + kbase + ac0;
    const float* pA1 = X + (size_t)gr1 * CIN + kbase + ac1;
    const unsigned short* pB0 = Wtb + ar0 * 2048 + kbase + ac0;
    const unsigned short* pB1 = Wtb + ar1 * 2048 + kbase + ac1;
    char* const LA = (char*)lA;
    char* const LB = (char*)lB;
    char* const wA0 = LA + ((ar0 * 128 + ac0 * 2) ^ ((ar0 & 7) << 4));
    char* const wA1 = LA + ((ar1 * 128 + ac1 * 2) ^ ((ar1 & 7) << 4));
    char* const wB0 = LB + ((ar0 * 128 + ac0 * 2) ^ ((ar0 & 7) << 4));
    char* const wB1 = LB + ((ar1 * 128 + ac1 * 2) ^ ((ar1 & 7) << 4));

    int aoff[4][2], boff[2];
#pragma unroll
    for (int m = 0; m < 4; ++m)
#pragma unroll
        for (int k = 0; k < 2; ++k)
            aoff[m][k] = (((m * 16 + lr) * 128 + k * 64 + lkb) ^ ((lr & 7) << 4));
#pragma unroll
    for (int k = 0; k < 2; ++k)
        boff[k] = (((w * 16 + lr) * 128 + k * 64 + lkb) ^ ((lr & 7) << 4));

    f32x4 acc[4];
#pragma unroll
    for (int m = 0; m < 4; ++m) acc[m] = (f32x4){0.f, 0.f, 0.f, 0.f};

    float4 a00, a01, a10, a11;
    ushort8 bv0, bv1;
    const float4 z4 = make_float4(0.f, 0.f, 0.f, 0.f);

#define STAGE_LOAD(S)                                                            \
    {                                                                            \
        bool v0 = (kbase + ac0 + (S) * 64) < CIN;                                \
        bool v1 = (kbase + ac1 + (S) * 64) < CIN;                                \
        const float4* q0 = (const float4*)(v0 ? pA0 + (S) * 64 : (const float*)X); \
        const float4* q1 = (const float4*)(v1 ? pA1 + (S) * 64 : (const float*)X); \
        a00 = q0[0]; a01 = q0[1];                                                \
        a10 = q1[0]; a11 = q1[1];                                                \
        if (!v0) { a00 = z4; a01 = z4; }                                         \
        if (!v1) { a10 = z4; a11 = z4; }                                         \
        bv0 = *(const ushort8*)(pB0 + (S) * 64);                                 \
        bv1 = *(const ushort8*)(pB1 + (S) * 64);                                 \
    }

    STAGE_LOAD(0)
    for (int s = 0; s < 16; ++s) {
        __syncthreads();
        *(ushort8*)wA0 = pack8(a00, a01);
        *(ushort8*)wA1 = pack8(a10, a11);
        *(ushort8*)wB0 = bv0;
        *(ushort8*)wB1 = bv1;
        __syncthreads();
        if (s < 15) STAGE_LOAD(s + 1)
#pragma unroll
        for (int k = 0; k < 2; ++k) {
            ushort8 bf = *(const ushort8*)(LB + boff[k]);
#pragma unroll
            for (int m = 0; m < 4; ++m) {
                ushort8 af = *(const ushort8*)(LA + aoff[m][k]);
                acc[m] = __builtin_amdgcn_mfma_f32_16x16x32_bf16(
                    __builtin_bit_cast(bf16x8, af), __builtin_bit_cast(bf16x8, bf),
                    acc[m], 0, 0, 0);
            }
        }
    }
#undef STAGE_LOAD
    float* Tp = Tpart + (size_t)kp * N_NODES * NHP;
    const int col = w * 16 + lr;
    const int rb = bm0 + (lane >> 4) * 4;
#pragma unroll
    for (int m = 0; m < 4; ++m)
#pragma unroll
        for (int rg = 0; rg < 4; ++rg) {
            int row = rb + m * 16 + rg;
            if (row < N_NODES) Tp[(size_t)row * NHP + col] = acc[m][rg];
        }
}

// ---------------- T = Tpart0 + Tpart1 (deterministic split-K reduce) ----------------
__global__ void reduce_T(const float4* __restrict__ Tp, float4* __restrict__ T) {
    int i = blockIdx.x * 256 + threadIdx.x;     // 320000 float4
    const int n4 = N_NODES * NHP / 4;
    if (i < n4) {
        float4 a = Tp[i], b = Tp[n4 + i];
        T[i] = make_float4(a.x + b.x, a.y + b.y, a.z + b.z, a.w + b.w);
    }
}

// ---------------- agg_a: U = A_hat @ T  (wave per node, lane = col) ----------------
__global__ __launch_bounds__(256) void agg_a(
    const float* __restrict__ T, const int* __restrict__ rowPtr,
    const int* __restrict__ colA, const float* __restrict__ valA,
    const float* __restrict__ dinv, float* __restrict__ U) {
    int wid = blockIdx.x * 4 + (threadIdx.x >> 6);
    int lane = threadIdx.x & 63;
    if (wid >= N_NODES) return;
    int d = wid;
    float dv = dinv[d];
    float acc = dv * dv * T[(size_t)d * NHP + lane];
    int e0 = rowPtr[d], e1 = rowPtr[d + 1];
    int e = e0;
    for (; e + 4 <= e1; e += 4) {
        int s0 = colA[e], s1 = colA[e + 1], s2 = colA[e + 2], s3 = colA[e + 3];
        float w0 = valA[e], w1 = valA[e + 1], w2 = valA[e + 2], w3 = valA[e + 3];
        float t0 = T[(size_t)s0 * NHP + lane];
        float t1 = T[(size_t)s1 * NHP + lane];
        float t2 = T[(size_t)s2 * NHP + lane];
        float t3 = T[(size_t)s3 * NHP + lane];
        acc += w0 * t0 + w1 * t1 + w2 * t2 + w3 * t3;
    }
    for (; e < e1; ++e) {
        int s = colA[e];
        acc += valA[e] * T[(size_t)s * NHP + lane];
    }
    U[(size_t)d * NHP + lane] = acc;
}

// ---------------- agg_b: out = act( A_hat @ U + rowsum(A_hat)*cc + dd ) ----------------
__global__ __launch_bounds__(256) void agg_b(
    const float* __restrict__ U, const int* __restrict__ rowPtr,
    const int* __restrict__ colA, const float* __restrict__ valA,
    const float* __restrict__ dinv, const float* __restrict__ ccdd,
    float* __restrict__ out) {
    int wid = blockIdx.x * 4 + (threadIdx.x >> 6);
    int lane = threadIdx.x & 63;
    if (wid >= N_NODES) return;
    int d = wid;
    float dv = dinv[d], self = dv * dv;
    float acc = self * U[(size_t)d * NHP + lane];
    float r = self;
    int e0 = rowPtr[d], e1 = rowPtr[d + 1];
    int e = e0;
    for (; e + 4 <= e1; e += 4) {
        int s0 = colA[e], s1 = colA[e + 1], s2 = colA[e + 2], s3 = colA[e + 3];
        float w0 = valA[e], w1 = valA[e + 1], w2 = valA[e + 2], w3 = valA[e + 3];
        float t0 = U[(size_t)s0 * NHP + lane];
        float t1 = U[(size_t)s1 * NHP + lane];
        float t2 = U[(size_t)s2 * NHP + lane];
        float t3 = U[(size_t)s3 * NHP + lane];
        acc += w0 * t0 + w1 * t1 + w2 * t2 + w3 * t3;
        r += w0 + w1 + w2 + w3;
    }
    for (; e < e1; ++e) {
        int s = colA[e];
        float wv = valA[e];
        acc += wv * U[(size_t)s * NHP + lane];
        r += wv;
    }
    if (lane < NH) {
        float v = acc + r * ccdd[lane] + ccdd[NHP + lane];
        if (lane < 2 || lane >= 18)   // mu_t, std_t, std_z get softplus; mu_z linear
            v = fmaxf(v, 0.f) + log1pf(expf(-fabsf(v)));
        size_t oidx;
        if (lane == 0)      oidx = (size_t)d;
        else if (lane == 1) oidx = (size_t)N_NODES + d;
        else if (lane < 18) oidx = (size_t)2 * N_NODES + (size_t)d * 16 + (lane - 2);
        else                oidx = (size_t)18 * N_NODES + (size_t)d * 16 + (lane - 18);
        out[oidx] = v;
    }
}

extern "C" void kernel_launch(void* const* d_in, const int* in_sizes, int n_in,
                              void* d_out, int out_size, void* d_ws, size_t ws_size,
                              hipStream_t stream) {
    const float* X   = (const float*)d_in[0];
    const int*   EI  = (const int*)d_in[1];
    const float* EW  = (const float*)d_in[2];
    const float* W1  = (const float*)d_in[3];
    const float* b1  = (const float*)d_in[4];
    const float* W2  = (const float*)d_in[5];
    const float* b2  = (const float*)d_in[6];
    const float* Wmt = (const float*)d_in[7];
    const float* bmt = (const float*)d_in[8];
    const float* Wst = (const float*)d_in[9];
    const float* bst = (const float*)d_in[10];
    const float* Wmz = (const float*)d_in[11];
    const float* bmz = (const float*)d_in[12];
    const float* Wsz = (const float*)d_in[13];
    const float* bsz = (const float*)d_in[14];
    float* out = (float*)d_out;

    char* ws = (char*)d_ws;
    size_t off = 0;
    auto alloc = [&](size_t bytes) -> char* {
        char* p = ws + off;
        off += (bytes + 255) & ~(size_t)255;
        return p;
    };
    unsigned short* W2b  = (unsigned short*)alloc((size_t)256 * 512 * 2);
    unsigned short* W1T  = (unsigned short*)alloc((size_t)2048 * 512 * 2);
    float*          W21f = (float*)alloc((size_t)256 * 2048 * 4);
    unsigned short* Wtb  = (unsigned short*)alloc((size_t)NHP * 2048 * 2);
    float*          ccdd = (float*)alloc(2 * NHP * 4);
    float*          Tp   = (float*)alloc((size_t)2 * N_NODES * NHP * 4);
    float*          T    = (float*)alloc((size_t)N_NODES * NHP * 4);
    float*          U    = (float*)alloc((size_t)N_NODES * NHP * 4);
    float* deg    = (float*)alloc(N_NODES * 4);
    float* dinv   = (float*)alloc(N_NODES * 4);
    int*   cnt    = (int*)alloc(N_NODES * 4);
    int*   cursor = (int*)alloc(N_NODES * 4);
    int*   rowPtr = (int*)alloc((N_NODES + 1) * 4);
    int*   colA   = (int*)alloc(N_EDGES * 4);
    float* valA   = (float*)alloc(N_EDGES * 4);
    if (off > ws_size) return;   // loud failure: d_out stays poisoned

    // graph prep
    k_init<<<(N_NODES + 255) / 256, 256, 0, stream>>>(deg, cnt, cursor);
    k_count<<<(N_EDGES + 255) / 256, 256, 0, stream>>>(EI, EW, deg, cnt);
    scan_dinv<<<1, 1024, 0, stream>>>(cnt, deg, dinv, rowPtr);
    k_fill<<<(N_EDGES + 255) / 256, 256, 0, stream>>>(EI, EW, dinv, rowPtr, cursor, colA, valA);

    // weight collapse: Wt = Wh @ W2 @ W1   (and cc/dd bias vectors)
    prep_w<<<256 + 1024, 256, 0, stream>>>(W2, W1, (unsigned int*)W2b, W1T);
    gemm_bt<float><<<dim3(16, 2), 256, 0, stream>>>(W2b, W1T, W21f, N2, 512, 512, 2048, 16);
    small_vec<<<1, 256, 0, stream>>>(W2, b1, b2, Wmt, bmt, Wst, bst, Wmz, bmz, Wsz, bsz, ccdd);
    wt_build<<<dim3(8, NHP), 256, 0, stream>>>(W21f, Wmt, Wst, Wmz, Wsz, Wtb);

    // T = X @ Wt^T  (split-K x2, f32 in, bf16 MFMA, f32 out)
    gemm_T<<<dim3(2, (N_NODES + 63) / 64), 256, 0, stream>>>(X, Wtb, Tp);
    reduce_T<<<(N_NODES * NHP / 4 + 255) / 256, 256, 0, stream>>>((const float4*)Tp, (float4*)T);

    // two 64-wide aggregations; second fuses bias terms + softplus + output layout
    agg_a<<<(N_NODES + 3) / 4, 256, 0, stream>>>(T, rowPtr, colA, valA, dinv, U);
    agg_b<<<(N_NODES + 3) / 4, 256, 0, stream>>>(U, rowPtr, colA, valA, dinv, ccdd, out);
}